// Round 8
// baseline (1075.620 us; speedup 1.0000x reference)
//
#include <hip/hip_runtime.h>
#include <hip/hip_fp16.h>
#include <math.h>

// RPMNet registration, fused persistent kernel, linear-domain Sinkhorn with
// K stored as fp16 in LDS (by design, not by spill). B=16, N=1024, feat 6;
// 3 reg iters x 5 sk iters. Grid 512 = 32 blocks/batch x 32 rows/block.
// Ksh[32][1024] fp16 = 64 KB/block; 2 blocks/CU (139.6 KB/CU < 160 KB).
// wu = 1/(1+K@wv) wave-local from LDS; wv via bank-swizzled LDS reduction +
// relaxed agent-scope fp32 atomicAdd into per-iteration pre-zeroed Sv buffers.
// All cross-block data via relaxed coherent-point atomics (R5-proven: no
// wbl2/inv L2 thrash). SVD redundant per block from identical accum bits.
//
// ws (floats): [0..767] accum[3][16][16] | [1024..1535 as u32] barriers
//              | [1536..] Sv[15][16][1024]  (all prep-zeroed each launch)

#define BATCH 16
#define NPTS  1024
#define REG_ITERS 3
#define SK_ITERS  5
#define EPS 1e-5f
#define LOG2E 1.44269504088896f

#define WS_ACC  0
#define WS_BARU 1024
#define WS_SV   1536
#define SV_STRIDE (BATCH * NPTS)
#define PREP_FLOATS (WS_SV + REG_ITERS * SK_ITERS * SV_STRIDE)  // 247296 = 966*256

__device__ __forceinline__ float ld_coh(const float* p) {
    return __hip_atomic_load((float*)p, __ATOMIC_RELAXED, __HIP_MEMORY_SCOPE_AGENT);
}
__device__ __forceinline__ void add_coh(float* p, float v) {
    __hip_atomic_fetch_add(p, v, __ATOMIC_RELAXED, __HIP_MEMORY_SCOPE_AGENT);
}

// relaxed spin barrier (R5/R6/R7-proven): no acquire/release cache maintenance.
__device__ __forceinline__ void batch_barrier(unsigned* bar, unsigned target) {
    __syncthreads();
    if (threadIdx.x == 0) {
        __builtin_amdgcn_s_waitcnt(0);   // drain my stores/atomics to coherent point
        __hip_atomic_fetch_add(bar, 1u, __ATOMIC_RELAXED, __HIP_MEMORY_SCOPE_AGENT);
        while (__hip_atomic_load(bar, __ATOMIC_RELAXED, __HIP_MEMORY_SCOPE_AGENT) < target)
            __builtin_amdgcn_s_sleep(2);
    }
    __syncthreads();
    __asm__ __volatile__("" ::: "memory");
}

// weighted Kabsch from 16 accum moments + old T -> new T (12 floats)
__device__ void kabsch_svd(const float* ac, const float* Told, float* Tnew) {
    double Sw = ac[0];
    double Sa[3] = {ac[1], ac[2], ac[3]};
    double Sb[3] = {ac[4], ac[5], ac[6]};
    double D  = Sw + (double)EPS;
    double ca0 = Sa[0]/D, ca1 = Sa[1]/D, ca2 = Sa[2]/D;
    double cb0 = Sb[0]/D, cb1 = Sb[1]/D, cb2 = Sb[2]/D;
    double f  = (2.0 - Sw / D) / D;
    double Am[3][3];
    for (int m = 0; m < 3; ++m)
        for (int n = 0; n < 3; ++n)
            Am[m][n] = (double)ac[7 + m*3 + n] - f * Sa[m] * Sb[n];
    double S[3][3];
    for (int i = 0; i < 3; ++i)
        for (int j = 0; j < 3; ++j) {
            double a2 = 0;
            for (int m = 0; m < 3; ++m) a2 += Am[m][i] * Am[m][j];
            S[i][j] = a2;
        }
    double V[3][3] = {{1,0,0},{0,1,0},{0,0,1}};
    const int prr[3] = {0,0,1}, qrr[3] = {1,2,2};
    for (int sweep = 0; sweep < 25; ++sweep) {
        double off = S[0][1]*S[0][1] + S[0][2]*S[0][2] + S[1][2]*S[1][2];
        if (off < 1e-28) break;
        for (int pi = 0; pi < 3; ++pi) {
            int p = prr[pi], q = qrr[pi];
            double apq = S[p][q];
            if (fabs(apq) < 1e-300) continue;
            double theta = (S[q][q] - S[p][p]) / (2.0 * apq);
            double tt = ((theta >= 0) ? 1.0 : -1.0) / (fabs(theta) + sqrt(theta*theta + 1.0));
            double cth = 1.0 / sqrt(tt*tt + 1.0), sth = tt * cth;
            for (int m = 0; m < 3; ++m) { double a1=S[m][p], a2=S[m][q]; S[m][p]=cth*a1-sth*a2; S[m][q]=sth*a1+cth*a2; }
            for (int m = 0; m < 3; ++m) { double a1=S[p][m], a2=S[q][m]; S[p][m]=cth*a1-sth*a2; S[q][m]=sth*a1+cth*a2; }
            for (int m = 0; m < 3; ++m) { double a1=V[m][p], a2=V[m][q]; V[m][p]=cth*a1-sth*a2; V[m][q]=sth*a1+cth*a2; }
        }
    }
    double lam[3] = {S[0][0], S[1][1], S[2][2]};
    int idx[3] = {0,1,2};
    if (lam[idx[0]] < lam[idx[1]]) { int t2=idx[0]; idx[0]=idx[1]; idx[1]=t2; }
    if (lam[idx[0]] < lam[idx[2]]) { int t2=idx[0]; idx[0]=idx[2]; idx[2]=t2; }
    if (lam[idx[1]] < lam[idx[2]]) { int t2=idx[1]; idx[1]=idx[2]; idx[2]=t2; }
    double Vs[3][3], sv[3];
    for (int i = 0; i < 3; ++i) {
        int c = idx[i];
        for (int m = 0; m < 3; ++m) Vs[m][i] = V[m][c];
        double l = lam[c]; sv[i] = sqrt(l > 0 ? l : 0);
    }
    double Us[3][3] = {{1,0,0},{0,1,0},{0,0,1}};
    double smax = sv[0] > 1e-300 ? sv[0] : 1e-300;
    for (int i = 0; i < 3; ++i) {
        double ux = Am[0][0]*Vs[0][i] + Am[0][1]*Vs[1][i] + Am[0][2]*Vs[2][i];
        double uy = Am[1][0]*Vs[0][i] + Am[1][1]*Vs[1][i] + Am[1][2]*Vs[2][i];
        double uz = Am[2][0]*Vs[0][i] + Am[2][1]*Vs[1][i] + Am[2][2]*Vs[2][i];
        if (sv[i] > 1e-12 * smax) {
            Us[0][i] = ux/sv[i]; Us[1][i] = uy/sv[i]; Us[2][i] = uz/sv[i];
        } else if (i == 2) {
            double cx = Us[1][0]*Us[2][1] - Us[2][0]*Us[1][1];
            double cy = Us[2][0]*Us[0][1] - Us[0][0]*Us[2][1];
            double cz = Us[0][0]*Us[1][1] - Us[1][0]*Us[0][1];
            double n = sqrt(cx*cx + cy*cy + cz*cz); n = n > 1e-300 ? n : 1.0;
            Us[0][i] = cx/n; Us[1][i] = cy/n; Us[2][i] = cz/n;
        }
    }
    double M[3][3];
    for (int m = 0; m < 3; ++m)
        for (int n = 0; n < 3; ++n)
            M[m][n] = Vs[m][0]*Us[n][0] + Vs[m][1]*Us[n][1] + Vs[m][2]*Us[n][2];
    double det = M[0][0]*(M[1][1]*M[2][2]-M[1][2]*M[2][1])
               - M[0][1]*(M[1][0]*M[2][2]-M[1][2]*M[2][0])
               + M[0][2]*(M[1][0]*M[2][1]-M[1][1]*M[2][0]);
    double g3 = (det > 0.0) ? 1.0 : -1.0;
    double R[3][3];
    for (int m = 0; m < 3; ++m)
        for (int n = 0; n < 3; ++n)
            R[m][n] = Vs[m][0]*Us[n][0] + Vs[m][1]*Us[n][1] + g3*Vs[m][2]*Us[n][2];
    double ti[3];
    ti[0] = -(R[0][0]*ca0 + R[0][1]*ca1 + R[0][2]*ca2) + cb0;
    ti[1] = -(R[1][0]*ca0 + R[1][1]*ca1 + R[1][2]*ca2) + cb1;
    ti[2] = -(R[2][0]*ca0 + R[2][1]*ca1 + R[2][2]*ca2) + cb2;
    double Ro[3][3] = {{Told[0],Told[1],Told[2]},{Told[4],Told[5],Told[6]},{Told[8],Told[9],Told[10]}};
    double to[3] = {Told[3], Told[7], Told[11]};
    for (int m = 0; m < 3; ++m) {
        for (int n = 0; n < 3; ++n)
            Tnew[m*4+n] = (float)(R[m][0]*Ro[0][n] + R[m][1]*Ro[1][n] + R[m][2]*Ro[2][n]);
        Tnew[m*4+3] = (float)(R[m][0]*to[0] + R[m][1]*to[1] + R[m][2]*to[2] + ti[m]);
    }
}

__global__ __launch_bounds__(256) void prep_kernel(float* ws) {
    int i = blockIdx.x * 256 + threadIdx.x;   // grid 966 x 256
    ws[i] = 0.f;
}

__global__ __launch_bounds__(256, 2) void rpm_kernel(
        const float* __restrict__ psrc, const float* __restrict__ pref,
        const float* __restrict__ beta, const float* __restrict__ alpha,
        float* __restrict__ ws, float* __restrict__ outT, float* __restrict__ perm)
{
    __shared__ __half2 Ksh[32][NPTS / 2];  // 64 KB: K rows of this block, fp16
    __shared__ float   svpf[NPTS];         // 4 KB, swizzled m = ((c&7)<<7)|(c>>3)
    __shared__ float   msum[16];
    __shared__ float   tT[12], tTn[12];

    const int blk = blockIdx.x, b = blk & 15, sub = blk >> 4;   // 32 blocks/batch
    const int tid = threadIdx.x, wid = tid >> 6, lane = tid & 63;
    const int grow = (b << 10) + (sub << 5) + (wid << 3);       // wave's first global row
    const int krow0 = wid << 3;                                  // wave's first block-local K row

    float*    accA = ws + WS_ACC;
    unsigned* bar  = (unsigned*)ws + WS_BARU + b * 32;
    float*    svA  = ws + WS_SV;
    unsigned  phase = 0;

    const float bet2 = beta[b] * LOG2E;
    const float alp  = alpha[b];
    const float tb2  = 2.f * bet2;

    if (tid < 12) tT[tid] = (tid == 0 || tid == 5 || tid == 10) ? 1.f : 0.f;
    __syncthreads();

    float wu[8];

    for (int it = 0; it < REG_ITERS; ++it) {
        const bool last = (it == REG_ITERS - 1);

        // ---- A) K-build: 2 row-groups of 4; K = exp2(aff2) -> fp16 LDS
        for (int rg = 0; rg < 2; ++rg) {
            float rx[4], ry[4], rz[4], g3[4], g4[4], g5[4], cr[4];
            #pragma unroll
            for (int rr = 0; rr < 4; ++rr) {
                const float* p = psrc + (size_t)(grow + rg*4 + rr) * 6;
                float x = p[0], y = p[1], z = p[2];
                float tx = tT[0]*x + tT[1]*y + tT[2]*z  + tT[3];
                float ty = tT[4]*x + tT[5]*y + tT[6]*z  + tT[7];
                float tz = tT[8]*x + tT[9]*y + tT[10]*z + tT[11];
                g3[rr]=p[3]; g4[rr]=p[4]; g5[rr]=p[5];
                rx[rr]=tx; ry[rr]=ty; rz[rr]=tz;
                float sq = tx*tx + ty*ty + tz*tz + g3[rr]*g3[rr] + g4[rr]*g4[rr] + g5[rr]*g5[rr];
                cr[rr] = bet2 * (alp - sq);
            }
            #pragma unroll
            for (int j = 0; j < 2; ++j) {
                const int cb = (lane << 3) + (j << 9);     // col base (8 cols)
                alignas(16) __half2 kh[4][4];
                #pragma unroll
                for (int i = 0; i < 4; ++i) {
                    const float* q = pref + ((size_t)(b << 10) + cb + 2*i) * 6;
                    float a0=q[0], a1=q[1], a2=q[2], a3=q[3], a4=q[4], a5=q[5];
                    float c0=q[6], c1=q[7], c2=q[8], c3=q[9], c4=q[10], c5=q[11];
                    float tk0 = bet2 * (a0*a0 + a1*a1 + a2*a2 + a3*a3 + a4*a4 + a5*a5);
                    float tk1 = bet2 * (c0*c0 + c1*c1 + c2*c2 + c3*c3 + c4*c4 + c5*c5);
                    #pragma unroll
                    for (int rr = 0; rr < 4; ++rr) {
                        float d0 = rx[rr]*a0 + ry[rr]*a1 + rz[rr]*a2
                                 + g3[rr]*a3 + g4[rr]*a4 + g5[rr]*a5;
                        float d1 = rx[rr]*c0 + ry[rr]*c1 + rz[rr]*c2
                                 + g3[rr]*c3 + g4[rr]*c4 + g5[rr]*c5;
                        float k0 = __builtin_amdgcn_exp2f(fmaf(tb2, d0, cr[rr] - tk0));
                        float k1 = __builtin_amdgcn_exp2f(fmaf(tb2, d1, cr[rr] - tk1));
                        kh[rr][i] = __floats2half2_rn(k0, k1);
                    }
                }
                #pragma unroll
                for (int rr = 0; rr < 4; ++rr)
                    *(float4*)&Ksh[krow0 + rg*4 + rr][(lane << 2) + (j << 8)] =
                        *(const float4*)&kh[rr][0];
            }
        }
        __syncthreads();   // K visible block-wide (v-pass/finalize read all rows? no —
                           // each wave reads only ITS rows; sync still needed for svp reuse ordering)

        // ---- B) 5 x (u-pass wave-local from LDS, v-pass -> swizzled LDS -> atomic Sv)
        for (int sk = 0; sk < SK_ITERS; ++sk) {
            float wv[16];
            if (sk == 0) {
                #pragma unroll
                for (int i = 0; i < 16; ++i) wv[i] = 1.f;
            } else {
                const float* sb = svA + (size_t)(it*SK_ITERS + sk - 1) * SV_STRIDE + (b << 10);
                #pragma unroll
                for (int i = 0; i < 16; ++i) {
                    int c = (lane << 3) + (i & 7) + ((i >> 3) << 9);
                    wv[i] = __builtin_amdgcn_rcpf(1.f + ld_coh(sb + c));
                }
            }
            #pragma unroll
            for (int r = 0; r < 8; ++r) {
                const __half2* kp = &Ksh[krow0 + r][lane << 2];
                float s = 0.f;
                #pragma unroll
                for (int t = 0; t < 4; ++t) {
                    float2 kk = __half22float2(kp[t]);
                    s = fmaf(kk.x, wv[2*t], fmaf(kk.y, wv[2*t+1], s));
                }
                #pragma unroll
                for (int t = 0; t < 4; ++t) {
                    float2 kk = __half22float2(kp[256 + t]);
                    s = fmaf(kk.x, wv[8 + 2*t], fmaf(kk.y, wv[8 + 2*t+1], s));
                }
                for (int off = 32; off; off >>= 1) s += __shfl_down(s, off);
                wu[r] = __builtin_amdgcn_rcpf(1.f + __shfl(s, 0));
            }
            // v-pass: per-lane column partials over this wave's 8 rows
            float pv[16];
            #pragma unroll
            for (int i = 0; i < 16; ++i) pv[i] = 0.f;
            #pragma unroll
            for (int r = 0; r < 8; ++r) {
                const __half2* kp = &Ksh[krow0 + r][lane << 2];
                const float w = wu[r];
                #pragma unroll
                for (int t = 0; t < 4; ++t) {
                    float2 kk = __half22float2(kp[t]);
                    pv[2*t]   = fmaf(kk.x, w, pv[2*t]);
                    pv[2*t+1] = fmaf(kk.y, w, pv[2*t+1]);
                }
                #pragma unroll
                for (int t = 0; t < 4; ++t) {
                    float2 kk = __half22float2(kp[256 + t]);
                    pv[8+2*t]   = fmaf(kk.x, w, pv[8+2*t]);
                    pv[8+2*t+1] = fmaf(kk.y, w, pv[8+2*t+1]);
                }
            }
            svpf[tid] = 0.f; svpf[tid+256] = 0.f; svpf[tid+512] = 0.f; svpf[tid+768] = 0.f;
            __syncthreads();
            #pragma unroll
            for (int i = 0; i < 16; ++i) {
                int cd = lane + ((i >> 3) << 6);           // c>>3
                atomicAdd(&svpf[((i & 7) << 7) | cd], pv[i]);
            }
            __syncthreads();
            float* vb = svA + (size_t)(it*SK_ITERS + sk) * SV_STRIDE + (b << 10);
            #pragma unroll
            for (int q = 0; q < 4; ++q) {
                int m = tid + (q << 8);
                int c = ((m & 127) << 3) | (m >> 7);
                add_coh(vb + c, svpf[m]);
            }
            batch_barrier(bar, 32u * (++phase));
        }

        // ---- C) finalize: perm (last iter) + moment accumulators
        {
            const float* sb = svA + (size_t)(it*SK_ITERS + SK_ITERS - 1) * SV_STRIDE + (b << 10);
            float wv[16], cx[16], cy[16], cz[16];
            #pragma unroll
            for (int i = 0; i < 16; ++i) {
                int c = (lane << 3) + (i & 7) + ((i >> 3) << 9);
                wv[i] = __builtin_amdgcn_rcpf(1.f + ld_coh(sb + c));
                const float* q = pref + ((size_t)(b << 10) + c) * 6;
                cx[i] = q[0]; cy[i] = q[1]; cz[i] = q[2];
            }
            float rx[8], ry[8], rz[8];
            #pragma unroll
            for (int r = 0; r < 8; ++r) {
                const float* p = psrc + (size_t)(grow + r) * 6;
                float x = p[0], y = p[1], z = p[2];
                rx[r] = tT[0]*x + tT[1]*y + tT[2]*z  + tT[3];
                ry[r] = tT[4]*x + tT[5]*y + tT[6]*z  + tT[7];
                rz[r] = tT[8]*x + tT[9]*y + tT[10]*z + tT[11];
            }
            if (tid < 16) msum[tid] = 0.f;
            __syncthreads();
            for (int r = 0; r < 8; ++r) {
                const __half2* kp = &Ksh[krow0 + r][lane << 2];
                const float w = wu[r];
                float pr[16];
                #pragma unroll
                for (int t = 0; t < 4; ++t) {
                    float2 kk = __half22float2(kp[t]);
                    pr[2*t]   = kk.x * w * wv[2*t];
                    pr[2*t+1] = kk.y * w * wv[2*t+1];
                }
                #pragma unroll
                for (int t = 0; t < 4; ++t) {
                    float2 kk = __half22float2(kp[256 + t]);
                    pr[8+2*t]   = kk.x * w * wv[8+2*t];
                    pr[8+2*t+1] = kk.y * w * wv[8+2*t+1];
                }
                float s=0.f, smx=0.f, smy=0.f, smz=0.f;
                #pragma unroll
                for (int i = 0; i < 16; ++i) {
                    s += pr[i]; smx = fmaf(pr[i], cx[i], smx);
                    smy = fmaf(pr[i], cy[i], smy); smz = fmaf(pr[i], cz[i], smz);
                }
                if (last) {
                    float* pb = perm + (size_t)(grow + r) * NPTS + (lane << 3);
                    *(float4*)pb         = make_float4(pr[0], pr[1], pr[2], pr[3]);
                    *(float4*)(pb + 4)   = make_float4(pr[4], pr[5], pr[6], pr[7]);
                    *(float4*)(pb + 512) = make_float4(pr[8], pr[9], pr[10], pr[11]);
                    *(float4*)(pb + 516) = make_float4(pr[12], pr[13], pr[14], pr[15]);
                }
                for (int off = 32; off; off >>= 1) {
                    s   += __shfl_down(s,   off);
                    smx += __shfl_down(smx, off);
                    smy += __shfl_down(smy, off);
                    smz += __shfl_down(smz, off);
                }
                if (lane == 0) {
                    float inv = 1.f / (s + EPS);
                    float bx = smx*inv, by = smy*inv, bz = smz*inv;
                    float fx = rx[r], fy = ry[r], fz = rz[r];
                    atomicAdd(&msum[0], s);
                    atomicAdd(&msum[1], s*fx);  atomicAdd(&msum[2], s*fy);  atomicAdd(&msum[3], s*fz);
                    atomicAdd(&msum[4], s*bx);  atomicAdd(&msum[5], s*by);  atomicAdd(&msum[6], s*bz);
                    atomicAdd(&msum[7], s*fx*bx);  atomicAdd(&msum[8],  s*fx*by);  atomicAdd(&msum[9],  s*fx*bz);
                    atomicAdd(&msum[10], s*fy*bx); atomicAdd(&msum[11], s*fy*by);  atomicAdd(&msum[12], s*fy*bz);
                    atomicAdd(&msum[13], s*fz*bx); atomicAdd(&msum[14], s*fz*by);  atomicAdd(&msum[15], s*fz*bz);
                }
            }
            __syncthreads();
            float* ac = accA + it * 256 + b * 16;
            if (tid < 16) add_coh(&ac[tid], msum[tid]);
            batch_barrier(bar, 32u * (++phase));

            // ---- D) SVD redundantly per block from identical accum bits
            if (!last || sub == 0) {
                if (tid == 0) {
                    float acl[16];
                    #pragma unroll
                    for (int i2 = 0; i2 < 16; ++i2) acl[i2] = ld_coh(&ac[i2]);
                    float Tl[12];
                    #pragma unroll
                    for (int i2 = 0; i2 < 12; ++i2) Tl[i2] = tT[i2];
                    kabsch_svd(acl, Tl, tTn);
                }
                __syncthreads();
                if (tid < 12) tT[tid] = tTn[tid];
                __syncthreads();
                if (last && tid == 0) {
                    #pragma unroll
                    for (int i2 = 0; i2 < 12; ++i2) outT[b * 12 + i2] = tT[i2];
                }
            }
        }
    }
}

extern "C" void kernel_launch(void* const* d_in, const int* in_sizes, int n_in,
                              void* d_out, int out_size, void* d_ws, size_t ws_size,
                              hipStream_t stream) {
    const float* psrc  = (const float*)d_in[0];
    const float* pref  = (const float*)d_in[1];
    const float* beta  = (const float*)d_in[2];
    const float* alpha = (const float*)d_in[3];

    float* out     = (float*)d_out;
    float* outT    = out;            // (16,3,4)
    float* outPerm = out + 192;      // (16,1024,1024)
    float* ws      = (float*)d_ws;

    prep_kernel<<<PREP_FLOATS / 256, 256, 0, stream>>>(ws);

    void* args[] = { (void*)&psrc, (void*)&pref, (void*)&beta, (void*)&alpha,
                     (void*)&ws, (void*)&outT, (void*)&outPerm };
    hipError_t ce = hipLaunchCooperativeKernel((const void*)rpm_kernel, dim3(512), dim3(256),
                                               args, 0, stream);
    if (ce != hipSuccess) {
        rpm_kernel<<<dim3(512), dim3(256), 0, stream>>>(psrc, pref, beta, alpha,
                                                        ws, outT, outPerm);
    }
}

// Round 9
// 949.546 us; speedup vs baseline: 1.1328x; 1.1328x over previous
//
#include <hip/hip_runtime.h>
#include <hip/hip_fp16.h>
#include <math.h>

// RPMNet registration, fused persistent kernel, linear-domain Sinkhorn with
// K stored as fp16 in LDS. B=16, N=1024, feat 6; 3 reg iters x 5 sk iters.
// Grid 512 = 32 blocks/batch x 32 rows/block. Ksh[32][1024] fp16 = 64 KB/block;
// 2 blocks/CU. ALL global coherent-point traffic (Sv read/publish) is
// tid-contiguous (R8's strided atomics cost 1.2 GB of sector fetches);
// lane-swizzled access happens only in LDS via padded swizzle f(c)=(c&7)*136+(c>>3).
// Cross-block data via relaxed agent-scope atomics only (no wbl2/inv).
//
// ws (floats): [0..767] accum[3][16][16] | [1024..1535 as u32] barriers
//              | [1536..] Sv[15][16][1024]  (all prep-zeroed each launch)

#define BATCH 16
#define NPTS  1024
#define REG_ITERS 3
#define SK_ITERS  5
#define EPS 1e-5f
#define LOG2E 1.44269504088896f

#define WS_ACC  0
#define WS_BARU 1024
#define WS_SV   1536
#define SV_STRIDE (BATCH * NPTS)
#define PREP_FLOATS (WS_SV + REG_ITERS * SK_ITERS * SV_STRIDE)  // 247296 = 966*256

__device__ __forceinline__ float ld_coh(const float* p) {
    return __hip_atomic_load((float*)p, __ATOMIC_RELAXED, __HIP_MEMORY_SCOPE_AGENT);
}
__device__ __forceinline__ void add_coh(float* p, float v) {
    __hip_atomic_fetch_add(p, v, __ATOMIC_RELAXED, __HIP_MEMORY_SCOPE_AGENT);
}

// relaxed spin barrier (R5-R8 proven): no acquire/release cache maintenance.
__device__ __forceinline__ void batch_barrier(unsigned* bar, unsigned target) {
    __syncthreads();
    if (threadIdx.x == 0) {
        __builtin_amdgcn_s_waitcnt(0);   // drain my stores/atomics to coherent point
        __hip_atomic_fetch_add(bar, 1u, __ATOMIC_RELAXED, __HIP_MEMORY_SCOPE_AGENT);
        while (__hip_atomic_load(bar, __ATOMIC_RELAXED, __HIP_MEMORY_SCOPE_AGENT) < target)
            __builtin_amdgcn_s_sleep(2);
    }
    __syncthreads();
    __asm__ __volatile__("" ::: "memory");
}

// weighted Kabsch from 16 accum moments + old T -> new T (12 floats)
__device__ void kabsch_svd(const float* ac, const float* Told, float* Tnew) {
    double Sw = ac[0];
    double Sa[3] = {ac[1], ac[2], ac[3]};
    double Sb[3] = {ac[4], ac[5], ac[6]};
    double D  = Sw + (double)EPS;
    double ca0 = Sa[0]/D, ca1 = Sa[1]/D, ca2 = Sa[2]/D;
    double cb0 = Sb[0]/D, cb1 = Sb[1]/D, cb2 = Sb[2]/D;
    double f  = (2.0 - Sw / D) / D;
    double Am[3][3];
    for (int m = 0; m < 3; ++m)
        for (int n = 0; n < 3; ++n)
            Am[m][n] = (double)ac[7 + m*3 + n] - f * Sa[m] * Sb[n];
    double S[3][3];
    for (int i = 0; i < 3; ++i)
        for (int j = 0; j < 3; ++j) {
            double a2 = 0;
            for (int m = 0; m < 3; ++m) a2 += Am[m][i] * Am[m][j];
            S[i][j] = a2;
        }
    double V[3][3] = {{1,0,0},{0,1,0},{0,0,1}};
    const int prr[3] = {0,0,1}, qrr[3] = {1,2,2};
    for (int sweep = 0; sweep < 25; ++sweep) {
        double off = S[0][1]*S[0][1] + S[0][2]*S[0][2] + S[1][2]*S[1][2];
        if (off < 1e-28) break;
        for (int pi = 0; pi < 3; ++pi) {
            int p = prr[pi], q = qrr[pi];
            double apq = S[p][q];
            if (fabs(apq) < 1e-300) continue;
            double theta = (S[q][q] - S[p][p]) / (2.0 * apq);
            double tt = ((theta >= 0) ? 1.0 : -1.0) / (fabs(theta) + sqrt(theta*theta + 1.0));
            double cth = 1.0 / sqrt(tt*tt + 1.0), sth = tt * cth;
            for (int m = 0; m < 3; ++m) { double a1=S[m][p], a2=S[m][q]; S[m][p]=cth*a1-sth*a2; S[m][q]=sth*a1+cth*a2; }
            for (int m = 0; m < 3; ++m) { double a1=S[p][m], a2=S[q][m]; S[p][m]=cth*a1-sth*a2; S[q][m]=sth*a1+cth*a2; }
            for (int m = 0; m < 3; ++m) { double a1=V[m][p], a2=V[m][q]; V[m][p]=cth*a1-sth*a2; V[m][q]=sth*a1+cth*a2; }
        }
    }
    double lam[3] = {S[0][0], S[1][1], S[2][2]};
    int idx[3] = {0,1,2};
    if (lam[idx[0]] < lam[idx[1]]) { int t2=idx[0]; idx[0]=idx[1]; idx[1]=t2; }
    if (lam[idx[0]] < lam[idx[2]]) { int t2=idx[0]; idx[0]=idx[2]; idx[2]=t2; }
    if (lam[idx[1]] < lam[idx[2]]) { int t2=idx[1]; idx[1]=idx[2]; idx[2]=t2; }
    double Vs[3][3], sv[3];
    for (int i = 0; i < 3; ++i) {
        int c = idx[i];
        for (int m = 0; m < 3; ++m) Vs[m][i] = V[m][c];
        double l = lam[c]; sv[i] = sqrt(l > 0 ? l : 0);
    }
    double Us[3][3] = {{1,0,0},{0,1,0},{0,0,1}};
    double smax = sv[0] > 1e-300 ? sv[0] : 1e-300;
    for (int i = 0; i < 3; ++i) {
        double ux = Am[0][0]*Vs[0][i] + Am[0][1]*Vs[1][i] + Am[0][2]*Vs[2][i];
        double uy = Am[1][0]*Vs[0][i] + Am[1][1]*Vs[1][i] + Am[1][2]*Vs[2][i];
        double uz = Am[2][0]*Vs[0][i] + Am[2][1]*Vs[1][i] + Am[2][2]*Vs[2][i];
        if (sv[i] > 1e-12 * smax) {
            Us[0][i] = ux/sv[i]; Us[1][i] = uy/sv[i]; Us[2][i] = uz/sv[i];
        } else if (i == 2) {
            double cx = Us[1][0]*Us[2][1] - Us[2][0]*Us[1][1];
            double cy = Us[2][0]*Us[0][1] - Us[0][0]*Us[2][1];
            double cz = Us[0][0]*Us[1][1] - Us[1][0]*Us[0][1];
            double n = sqrt(cx*cx + cy*cy + cz*cz); n = n > 1e-300 ? n : 1.0;
            Us[0][i] = cx/n; Us[1][i] = cy/n; Us[2][i] = cz/n;
        }
    }
    double M[3][3];
    for (int m = 0; m < 3; ++m)
        for (int n = 0; n < 3; ++n)
            M[m][n] = Vs[m][0]*Us[n][0] + Vs[m][1]*Us[n][1] + Vs[m][2]*Us[n][2];
    double det = M[0][0]*(M[1][1]*M[2][2]-M[1][2]*M[2][1])
               - M[0][1]*(M[1][0]*M[2][2]-M[1][2]*M[2][0])
               + M[0][2]*(M[1][0]*M[2][1]-M[1][1]*M[2][0]);
    double g3 = (det > 0.0) ? 1.0 : -1.0;
    double R[3][3];
    for (int m = 0; m < 3; ++m)
        for (int n = 0; n < 3; ++n)
            R[m][n] = Vs[m][0]*Us[n][0] + Vs[m][1]*Us[n][1] + g3*Vs[m][2]*Us[n][2];
    double ti[3];
    ti[0] = -(R[0][0]*ca0 + R[0][1]*ca1 + R[0][2]*ca2) + cb0;
    ti[1] = -(R[1][0]*ca0 + R[1][1]*ca1 + R[1][2]*ca2) + cb1;
    ti[2] = -(R[2][0]*ca0 + R[2][1]*ca1 + R[2][2]*ca2) + cb2;
    double Ro[3][3] = {{Told[0],Told[1],Told[2]},{Told[4],Told[5],Told[6]},{Told[8],Told[9],Told[10]}};
    double to[3] = {Told[3], Told[7], Told[11]};
    for (int m = 0; m < 3; ++m) {
        for (int n = 0; n < 3; ++n)
            Tnew[m*4+n] = (float)(R[m][0]*Ro[0][n] + R[m][1]*Ro[1][n] + R[m][2]*Ro[2][n]);
        Tnew[m*4+3] = (float)(R[m][0]*to[0] + R[m][1]*to[1] + R[m][2]*to[2] + ti[m]);
    }
}

__global__ __launch_bounds__(256) void prep_kernel(float* ws) {
    int i = blockIdx.x * 256 + threadIdx.x;   // grid 966 x 256
    ws[i] = 0.f;
}

// padded swizzle: column c of this batch lives at LDS index f(c)
__device__ __forceinline__ int swz(int c) { return (c & 7) * 136 + (c >> 3); }

__global__ __launch_bounds__(256, 2) void rpm_kernel(
        const float* __restrict__ psrc, const float* __restrict__ pref,
        const float* __restrict__ beta, const float* __restrict__ alpha,
        float* __restrict__ ws, float* __restrict__ outT, float* __restrict__ perm)
{
    __shared__ __half2 Ksh[32][NPTS / 2];  // 64 KB: this block's 32 K rows, fp16
    __shared__ float   wvb[1088];          // staged wv, padded swizzle
    __shared__ float   svpf[1088];         // column partial sums, padded swizzle
    __shared__ float   msum[16];
    __shared__ float   tT[12], tTn[12];

    const int blk = blockIdx.x, b = blk & 15, sub = blk >> 4;   // 32 blocks/batch
    const int tid = threadIdx.x, wid = tid >> 6, lane = tid & 63;
    const int grow = (b << 10) + (sub << 5) + (wid << 3);       // wave's first global row
    const int krow0 = wid << 3;

    float*    accA = ws + WS_ACC;
    unsigned* bar  = (unsigned*)ws + WS_BARU + b * 32;
    float*    svA  = ws + WS_SV;
    unsigned  phase = 0;

    const float bet2 = beta[b] * LOG2E;
    const float alp  = alpha[b];
    const float tb2  = 2.f * bet2;

    if (tid < 12) tT[tid] = (tid == 0 || tid == 5 || tid == 10) ? 1.f : 0.f;
    __syncthreads();

    float wu[8];

    for (int it = 0; it < REG_ITERS; ++it) {
        const bool last = (it == REG_ITERS - 1);

        // ---- A) K-build: K = exp2(aff2) -> fp16 LDS (2 row-groups of 4)
        for (int rg = 0; rg < 2; ++rg) {
            float rx[4], ry[4], rz[4], g3[4], g4[4], g5[4], cr[4];
            #pragma unroll
            for (int rr = 0; rr < 4; ++rr) {
                const float* p = psrc + (size_t)(grow + rg*4 + rr) * 6;
                float x = p[0], y = p[1], z = p[2];
                float tx = tT[0]*x + tT[1]*y + tT[2]*z  + tT[3];
                float ty = tT[4]*x + tT[5]*y + tT[6]*z  + tT[7];
                float tz = tT[8]*x + tT[9]*y + tT[10]*z + tT[11];
                g3[rr]=p[3]; g4[rr]=p[4]; g5[rr]=p[5];
                rx[rr]=tx; ry[rr]=ty; rz[rr]=tz;
                float sq = tx*tx + ty*ty + tz*tz + g3[rr]*g3[rr] + g4[rr]*g4[rr] + g5[rr]*g5[rr];
                cr[rr] = bet2 * (alp - sq);
            }
            #pragma unroll
            for (int j = 0; j < 2; ++j) {
                const int cb = (lane << 3) + (j << 9);     // col base (8 cols)
                alignas(16) __half2 kh[4][4];
                #pragma unroll
                for (int i = 0; i < 4; ++i) {
                    const float* q = pref + ((size_t)(b << 10) + cb + 2*i) * 6;
                    float a0=q[0], a1=q[1], a2=q[2], a3=q[3], a4=q[4], a5=q[5];
                    float c0=q[6], c1=q[7], c2=q[8], c3=q[9], c4=q[10], c5=q[11];
                    float tk0 = bet2 * (a0*a0 + a1*a1 + a2*a2 + a3*a3 + a4*a4 + a5*a5);
                    float tk1 = bet2 * (c0*c0 + c1*c1 + c2*c2 + c3*c3 + c4*c4 + c5*c5);
                    #pragma unroll
                    for (int rr = 0; rr < 4; ++rr) {
                        float d0 = rx[rr]*a0 + ry[rr]*a1 + rz[rr]*a2
                                 + g3[rr]*a3 + g4[rr]*a4 + g5[rr]*a5;
                        float d1 = rx[rr]*c0 + ry[rr]*c1 + rz[rr]*c2
                                 + g3[rr]*c3 + g4[rr]*c4 + g5[rr]*c5;
                        float k0 = __builtin_amdgcn_exp2f(fmaf(tb2, d0, cr[rr] - tk0));
                        float k1 = __builtin_amdgcn_exp2f(fmaf(tb2, d1, cr[rr] - tk1));
                        kh[rr][i] = __floats2half2_rn(k0, k1);
                    }
                }
                #pragma unroll
                for (int rr = 0; rr < 4; ++rr)
                    *(float4*)&Ksh[krow0 + rg*4 + rr][(lane << 2) + (j << 8)] =
                        *(const float4*)&kh[rr][0];
            }
        }

        // ---- B) 5 x (stage wv, u-pass, v-pass -> LDS swizzle -> contiguous add)
        for (int sk = 0; sk < SK_ITERS; ++sk) {
            // phase 1: zero svpf; stage wv coalesced (tid-linear global reads)
            #pragma unroll
            for (int q = 0; q < 4; ++q) svpf[tid + (q << 8)] = 0.f;
            if (tid < 64) svpf[1024 + tid] = 0.f;
            if (sk > 0) {
                const float* sb = svA + (size_t)(it*SK_ITERS + sk - 1) * SV_STRIDE + (b << 10);
                #pragma unroll
                for (int q = 0; q < 4; ++q) {
                    int c = tid + (q << 8);
                    wvb[swz(c)] = __builtin_amdgcn_rcpf(1.f + ld_coh(sb + c));
                }
            }
            __syncthreads();

            float wv[16];
            if (sk == 0) {
                #pragma unroll
                for (int i = 0; i < 16; ++i) wv[i] = 1.f;
            } else {
                #pragma unroll
                for (int i = 0; i < 16; ++i)
                    wv[i] = wvb[(i & 7) * 136 + lane + ((i >> 3) << 6)];
            }
            // u-pass: wave-local row sums from LDS K
            #pragma unroll
            for (int r = 0; r < 8; ++r) {
                const __half2* kp = &Ksh[krow0 + r][lane << 2];
                float s = 0.f;
                #pragma unroll
                for (int t = 0; t < 4; ++t) {
                    float2 kk = __half22float2(kp[t]);
                    s = fmaf(kk.x, wv[2*t], fmaf(kk.y, wv[2*t+1], s));
                }
                #pragma unroll
                for (int t = 0; t < 4; ++t) {
                    float2 kk = __half22float2(kp[256 + t]);
                    s = fmaf(kk.x, wv[8 + 2*t], fmaf(kk.y, wv[8 + 2*t+1], s));
                }
                for (int off = 32; off; off >>= 1) s += __shfl_down(s, off);
                wu[r] = __builtin_amdgcn_rcpf(1.f + __shfl(s, 0));
            }
            // v-pass: per-lane column partials over this wave's 8 rows
            float pv[16];
            #pragma unroll
            for (int i = 0; i < 16; ++i) pv[i] = 0.f;
            #pragma unroll
            for (int r = 0; r < 8; ++r) {
                const __half2* kp = &Ksh[krow0 + r][lane << 2];
                const float w = wu[r];
                #pragma unroll
                for (int t = 0; t < 4; ++t) {
                    float2 kk = __half22float2(kp[t]);
                    pv[2*t]   = fmaf(kk.x, w, pv[2*t]);
                    pv[2*t+1] = fmaf(kk.y, w, pv[2*t+1]);
                }
                #pragma unroll
                for (int t = 0; t < 4; ++t) {
                    float2 kk = __half22float2(kp[256 + t]);
                    pv[8+2*t]   = fmaf(kk.x, w, pv[8+2*t]);
                    pv[8+2*t+1] = fmaf(kk.y, w, pv[8+2*t+1]);
                }
            }
            #pragma unroll
            for (int i = 0; i < 16; ++i)   // bank = (lane + const) % 32: conflict-free
                atomicAdd(&svpf[(i & 7) * 136 + lane + ((i >> 3) << 6)], pv[i]);
            __syncthreads();
            // phase 3: publish contiguously (tid-linear global atomics)
            float* vb = svA + (size_t)(it*SK_ITERS + sk) * SV_STRIDE + (b << 10);
            #pragma unroll
            for (int q = 0; q < 4; ++q) {
                int c = tid + (q << 8);
                add_coh(vb + c, svpf[swz(c)]);
            }
            batch_barrier(bar, 32u * (++phase));
        }

        // ---- C) finalize: perm (last iter) + moment accumulators
        {
            const float* sb = svA + (size_t)(it*SK_ITERS + SK_ITERS - 1) * SV_STRIDE + (b << 10);
            #pragma unroll
            for (int q = 0; q < 4; ++q) {
                int c = tid + (q << 8);
                wvb[swz(c)] = __builtin_amdgcn_rcpf(1.f + ld_coh(sb + c));
            }
            if (tid < 16) msum[tid] = 0.f;
            __syncthreads();
            float wv[16], cx[16], cy[16], cz[16];
            #pragma unroll
            for (int i = 0; i < 16; ++i) {
                int c = (lane << 3) + (i & 7) + ((i >> 3) << 9);
                wv[i] = wvb[(i & 7) * 136 + lane + ((i >> 3) << 6)];
                const float* q = pref + ((size_t)(b << 10) + c) * 6;   // L1/L2-cached
                cx[i] = q[0]; cy[i] = q[1]; cz[i] = q[2];
            }
            float rx[8], ry[8], rz[8];
            #pragma unroll
            for (int r = 0; r < 8; ++r) {
                const float* p = psrc + (size_t)(grow + r) * 6;
                float x = p[0], y = p[1], z = p[2];
                rx[r] = tT[0]*x + tT[1]*y + tT[2]*z  + tT[3];
                ry[r] = tT[4]*x + tT[5]*y + tT[6]*z  + tT[7];
                rz[r] = tT[8]*x + tT[9]*y + tT[10]*z + tT[11];
            }
            for (int r = 0; r < 8; ++r) {
                const __half2* kp = &Ksh[krow0 + r][lane << 2];
                const float w = wu[r];
                float pr[16];
                #pragma unroll
                for (int t = 0; t < 4; ++t) {
                    float2 kk = __half22float2(kp[t]);
                    pr[2*t]   = kk.x * w * wv[2*t];
                    pr[2*t+1] = kk.y * w * wv[2*t+1];
                }
                #pragma unroll
                for (int t = 0; t < 4; ++t) {
                    float2 kk = __half22float2(kp[256 + t]);
                    pr[8+2*t]   = kk.x * w * wv[8+2*t];
                    pr[8+2*t+1] = kk.y * w * wv[8+2*t+1];
                }
                float s=0.f, smx=0.f, smy=0.f, smz=0.f;
                #pragma unroll
                for (int i = 0; i < 16; ++i) {
                    s += pr[i]; smx = fmaf(pr[i], cx[i], smx);
                    smy = fmaf(pr[i], cy[i], smy); smz = fmaf(pr[i], cz[i], smz);
                }
                if (last) {
                    float* pb = perm + (size_t)(grow + r) * NPTS + (lane << 3);
                    *(float4*)pb         = make_float4(pr[0], pr[1], pr[2], pr[3]);
                    *(float4*)(pb + 4)   = make_float4(pr[4], pr[5], pr[6], pr[7]);
                    *(float4*)(pb + 512) = make_float4(pr[8], pr[9], pr[10], pr[11]);
                    *(float4*)(pb + 516) = make_float4(pr[12], pr[13], pr[14], pr[15]);
                }
                for (int off = 32; off; off >>= 1) {
                    s   += __shfl_down(s,   off);
                    smx += __shfl_down(smx, off);
                    smy += __shfl_down(smy, off);
                    smz += __shfl_down(smz, off);
                }
                if (lane == 0) {
                    float inv = 1.f / (s + EPS);
                    float bx = smx*inv, by = smy*inv, bz = smz*inv;
                    float fx = rx[r], fy = ry[r], fz = rz[r];
                    atomicAdd(&msum[0], s);
                    atomicAdd(&msum[1], s*fx);  atomicAdd(&msum[2], s*fy);  atomicAdd(&msum[3], s*fz);
                    atomicAdd(&msum[4], s*bx);  atomicAdd(&msum[5], s*by);  atomicAdd(&msum[6], s*bz);
                    atomicAdd(&msum[7], s*fx*bx);  atomicAdd(&msum[8],  s*fx*by);  atomicAdd(&msum[9],  s*fx*bz);
                    atomicAdd(&msum[10], s*fy*bx); atomicAdd(&msum[11], s*fy*by);  atomicAdd(&msum[12], s*fy*bz);
                    atomicAdd(&msum[13], s*fz*bx); atomicAdd(&msum[14], s*fz*by);  atomicAdd(&msum[15], s*fz*bz);
                }
            }
            __syncthreads();
            float* ac = accA + it * 256 + b * 16;
            if (tid < 16) add_coh(&ac[tid], msum[tid]);
            batch_barrier(bar, 32u * (++phase));

            // ---- D) SVD redundantly per block from identical accum bits
            if (!last || sub == 0) {
                if (tid == 0) {
                    float acl[16];
                    #pragma unroll
                    for (int i2 = 0; i2 < 16; ++i2) acl[i2] = ld_coh(&ac[i2]);
                    float Tl[12];
                    #pragma unroll
                    for (int i2 = 0; i2 < 12; ++i2) Tl[i2] = tT[i2];
                    kabsch_svd(acl, Tl, tTn);
                }
                __syncthreads();
                if (tid < 12) tT[tid] = tTn[tid];
                __syncthreads();
                if (last && tid == 0) {
                    #pragma unroll
                    for (int i2 = 0; i2 < 12; ++i2) outT[b * 12 + i2] = tT[i2];
                }
            }
        }
    }
}

extern "C" void kernel_launch(void* const* d_in, const int* in_sizes, int n_in,
                              void* d_out, int out_size, void* d_ws, size_t ws_size,
                              hipStream_t stream) {
    const float* psrc  = (const float*)d_in[0];
    const float* pref  = (const float*)d_in[1];
    const float* beta  = (const float*)d_in[2];
    const float* alpha = (const float*)d_in[3];

    float* out     = (float*)d_out;
    float* outT    = out;            // (16,3,4)
    float* outPerm = out + 192;      // (16,1024,1024)
    float* ws      = (float*)d_ws;

    prep_kernel<<<PREP_FLOATS / 256, 256, 0, stream>>>(ws);

    void* args[] = { (void*)&psrc, (void*)&pref, (void*)&beta, (void*)&alpha,
                     (void*)&ws, (void*)&outT, (void*)&outPerm };
    hipError_t ce = hipLaunchCooperativeKernel((const void*)rpm_kernel, dim3(512), dim3(256),
                                               args, 0, stream);
    if (ce != hipSuccess) {
        rpm_kernel<<<dim3(512), dim3(256), 0, stream>>>(psrc, pref, beta, alpha,
                                                        ws, outT, outPerm);
    }
}